// Round 1
// baseline (8421.907 us; speedup 1.0000x reference)
//
#include <hip/hip_runtime.h>

// GTS forecasting (DCGRU enc-dec over dense 10000x10000 adjacency), gfx950.
// Key restructuring: rank-1 embedding => all heavy diffusion is width-64 bf16
// MFMA passes over A (bf16, 200MB, L3-resident). 4 heavy passes per cell.
// Small projections (K=256) fused into one MFMA kernel w/ GRU epilogue.

typedef unsigned short u16;
typedef __attribute__((ext_vector_type(8))) short short8;
typedef __attribute__((ext_vector_type(8))) unsigned short u16x8;
typedef __attribute__((ext_vector_type(4))) float f32x4;

#define NN 10000
#define MPAD 10112   // 79*128
#define KPAD 10048   // 157*64
#define SPLITS 13
#define KSPLIT 768   // 12 k-steps of 64; last split takes 13

__device__ __forceinline__ u16 f2bf(float f) {
  unsigned u = __float_as_uint(f);
  unsigned r = (u + 0x7FFFu + ((u >> 16) & 1u)) >> 16;
  return (u16)r;
}

__device__ __forceinline__ void load_lds16(const void* g, void* l) {
  __builtin_amdgcn_global_load_lds(
      (__attribute__((address_space(1))) void*)(void*)g,
      (__attribute__((address_space(3))) void*)l, 16, 0, 0);
}

// ---------------- fp32 -> bf16 convert of adjacency ----------------
__global__ __launch_bounds__(256) void cvt_bf16(const float* __restrict__ a,
                                                u16* __restrict__ o) {
  long i = ((long)blockIdx.x * 256 + threadIdx.x) * 8;
  if (i >= 100000000L) return;
  float4 x = *(const float4*)(a + i);
  float4 y = *(const float4*)(a + i + 4);
  u16x8 v;
  v[0]=f2bf(x.x); v[1]=f2bf(x.y); v[2]=f2bf(x.z); v[3]=f2bf(x.w);
  v[4]=f2bf(y.x); v[5]=f2bf(y.y); v[6]=f2bf(y.z); v[7]=f2bf(y.w);
  *(u16x8*)(o + i) = v;
}

// ---------------- transpose+convert B operand: Ht[c][k] = src[k][c] ----------
__global__ __launch_bounds__(256) void prep_bt(const float* __restrict__ src,
    int sstride, int ncols, int nrows, u16* __restrict__ Ht) {
  int total = nrows * KPAD;
  for (int e = blockIdx.x * 256 + threadIdx.x; e < total; e += gridDim.x * 256) {
    int c = e / KPAD, k = e - c * KPAD;
    float v = (k < NN && c < ncols) ? src[(long)k * sstride + c] : 0.f;
    Ht[e] = f2bf(v);
  }
}

// ---------------- combined weight builders ----------------
// Wt[j][k], k<256: [W0h-W2h | W1h | 2*W2h | rank1 rows p0-p2,p1,2*p2]
__global__ void build_w_enc(const float* __restrict__ W, const float* __restrict__ wemb,
    const float* __restrict__ bemb, const float* __restrict__ bsrc, int nout,
    u16* __restrict__ Wt, float* __restrict__ biasout) {
  int j = blockIdx.x, k = threadIdx.x;
  float v = 0.f;
  if (k < 64)        v = W[(64 + k) * nout + j] - W[(320 + k) * nout + j];
  else if (k < 128)  v = W[(192 + (k - 64)) * nout + j];
  else if (k < 192)  v = 2.f * W[(320 + (k - 128)) * nout + j];
  else if (k == 192) { float s = 0; for (int i = 0; i < 64; i++) s += wemb[i] * (W[i*nout+j] - W[(256+i)*nout+j]); v = s; }
  else if (k == 193) { float s = 0; for (int i = 0; i < 64; i++) s += wemb[i] * W[(128+i)*nout+j]; v = s; }
  else if (k == 194) { float s = 0; for (int i = 0; i < 64; i++) s += wemb[i] * W[(256+i)*nout+j]; v = 2.f * s; }
  Wt[j * 256 + k] = f2bf(v);
  if (k == 195) {
    float bb = bsrc[j];
    for (int i = 0; i < 64; i++) bb += bemb[i] * (W[i*nout+j] + W[(128+i)*nout+j] + W[(256+i)*nout+j]);
    biasout[j] = bb;
  }
}

__global__ void build_w_dec(const float* __restrict__ W, int nout, u16* __restrict__ Wt) {
  int j = blockIdx.x, k = threadIdx.x;
  float v = 0.f;
  if (k < 64)        v = W[(1 + k) * nout + j] - W[(131 + k) * nout + j];
  else if (k < 128)  v = W[(66 + (k - 64)) * nout + j];
  else if (k < 192)  v = 2.f * W[(131 + (k - 128)) * nout + j];
  else if (k == 192) v = W[0 * nout + j] - W[130 * nout + j];
  else if (k == 193) v = W[65 * nout + j];
  else if (k == 194) v = 2.f * W[130 * nout + j];
  Wt[j * 256 + k] = f2bf(v);
}

// ---------------- heavy pass: C(+=) A(10000x10000,bf16) @ Ht^T ----------------
// grid (79, SPLITS), block 256. split-K with fp32 atomicAdd into pre-zeroed C.
__global__ __launch_bounds__(256) void gemm_bt(
    const u16* __restrict__ A, const u16* __restrict__ Ht,
    float* __restrict__ C, int ntiles, int cstride) {
  __shared__ u16 Al[128 * 64];
  __shared__ u16 Bl[96 * 64];
  int tid = threadIdx.x;
  int wave = tid >> 6, lane = tid & 63, ml = lane & 15, q = lane >> 4;
  int row0 = blockIdx.x * 128;
  int kb = blockIdx.y * KSPLIT;
  int ke = (blockIdx.y == SPLITS - 1) ? KPAD : kb + KSPLIT;
  f32x4 acc[2][5] = {};
  int r8 = tid >> 3, c8 = tid & 7;
  int nrows_b = ntiles * 16;
  int biss = (nrows_b + 31) >> 5;
  for (int k0 = kb; k0 < ke; k0 += 64) {
    int kch = k0 + c8 * 8;
    int kcA = kch > 9992 ? 9992 : kch;  // clamp; B is zero-padded past 10000
#pragma unroll
    for (int is = 0; is < 4; is++) {
      int row = row0 + is * 32 + r8;
      row = row > 9999 ? 9999 : row;
      load_lds16(A + (size_t)row * NN + kcA, (u16*)Al + is * 2048 + wave * 512);
    }
    for (int is = 0; is < biss; is++) {
      int br = is * 32 + r8;
      br = br >= nrows_b ? nrows_b - 1 : br;
      load_lds16(Ht + (size_t)br * KPAD + k0 + c8 * 8, (u16*)Bl + is * 2048 + wave * 512);
    }
    __syncthreads();
#pragma unroll
    for (int kh = 0; kh < 2; kh++) {
      short8 a0 = *(const short8*)(Al + (wave * 32 + ml) * 64 + kh * 32 + q * 8);
      short8 a1 = *(const short8*)(Al + (wave * 32 + 16 + ml) * 64 + kh * 32 + q * 8);
#pragma unroll
      for (int nt = 0; nt < 5; nt++) {
        if (nt < ntiles) {
          short8 b = *(const short8*)(Bl + (nt * 16 + ml) * 64 + kh * 32 + q * 8);
          acc[0][nt] = __builtin_amdgcn_mfma_f32_16x16x32_bf16(a0, b, acc[0][nt], 0, 0, 0);
          acc[1][nt] = __builtin_amdgcn_mfma_f32_16x16x32_bf16(a1, b, acc[1][nt], 0, 0, 0);
        }
      }
    }
    __syncthreads();
  }
#pragma unroll
  for (int mt = 0; mt < 2; mt++)
#pragma unroll
    for (int nt = 0; nt < 5; nt++)
      if (nt < ntiles)
#pragma unroll
        for (int i = 0; i < 4; i++) {
          int m = row0 + wave * 32 + mt * 16 + q * 4 + i;
          atomicAdd(&C[(size_t)m * cstride + nt * 16 + ml], acc[mt][nt][i]);
        }
}

// ---------------- fused cell projection (K=256) + GRU epilogue ----------------
// G = src0@(W0h-W2h) + C1@W1h + C2@(2W2h) + rank1(scalars) + bias
// mode 0 (gate): r=sig(G[:,:64]) -> rh = r*h;  u=sig(G[:,64:]) -> ubuf
// mode 1 (cand): c=tanh(G); hout = u*h + (1-u)*c
// Also: saves decoder scalars (C1[:,64],C2[:,64]) then zeroes C1,C2 for reuse.
__global__ __launch_bounds__(256) void cellmm(
    const float* __restrict__ src0, int s0s,
    const float* __restrict__ C1s, const float* __restrict__ C2s,
    const float* __restrict__ sc0, int ss0,
    const float* __restrict__ sc1, int ss1,
    const float* __restrict__ sc2, int ss2,
    const u16* __restrict__ Wt, const float* __restrict__ bias,
    int ntiles, int mode,
    const float* __restrict__ hstate, int hstride,
    float* __restrict__ out0, int out0s,
    float* __restrict__ ubuf,
    float* __restrict__ zero1, float* __restrict__ zero2,
    float* __restrict__ sdec) {
  __shared__ u16 Al[128 * 64];
  __shared__ u16 Wl[128 * 64];
  int tid = threadIdx.x;
  int wave = tid >> 6, lane = tid & 63, ml = lane & 15, q = lane >> 4;
  int row0 = blockIdx.x * 128;
  f32x4 acc[2][8] = {};
  for (int kc = 0; kc < 4; kc++) {
    int k0 = kc * 64;
    {
      int r = tid >> 1, half = tid & 1;
      int m = row0 + r;
      u16* dst = Al + r * 64 + half * 32;
      if (kc < 3) {
        const float* sp; int st;
        if (kc == 0) { sp = src0; st = s0s; }
        else if (kc == 1) { sp = C1s; st = 80; }
        else { sp = C2s; st = 80; }
        const float* p = sp + (size_t)m * st + half * 32;
#pragma unroll
        for (int jj = 0; jj < 32; jj += 4) {
          float4 f = *(const float4*)(p + jj);
          dst[jj + 0] = f2bf(f.x); dst[jj + 1] = f2bf(f.y);
          dst[jj + 2] = f2bf(f.z); dst[jj + 3] = f2bf(f.w);
        }
      } else {
        if (half == 0) {
          int mc = m > 9999 ? 9999 : m;
          dst[0] = f2bf(sc0[(size_t)mc * ss0]);
          dst[1] = f2bf(sc1[(size_t)mc * ss1]);
          dst[2] = f2bf(sc2[(size_t)mc * ss2]);
          for (int jj = 3; jj < 32; jj++) dst[jj] = 0;
        } else {
          for (int jj = 0; jj < 32; jj++) dst[jj] = 0;
        }
      }
    }
    int wiss = ntiles >> 1;
    for (int is = 0; is < wiss; is++) {
      int jr = is * 32 + (tid >> 3);
      load_lds16(Wt + (size_t)jr * 256 + k0 + (tid & 7) * 8, (u16*)Wl + is * 2048 + wave * 512);
    }
    __syncthreads();
#pragma unroll
    for (int kh = 0; kh < 2; kh++) {
      short8 a0 = *(const short8*)(Al + (wave * 32 + ml) * 64 + kh * 32 + q * 8);
      short8 a1 = *(const short8*)(Al + (wave * 32 + 16 + ml) * 64 + kh * 32 + q * 8);
#pragma unroll
      for (int nt = 0; nt < 8; nt++) {
        if (nt < ntiles) {
          short8 b = *(const short8*)(Wl + (nt * 16 + ml) * 64 + kh * 32 + q * 8);
          acc[0][nt] = __builtin_amdgcn_mfma_f32_16x16x32_bf16(a0, b, acc[0][nt], 0, 0, 0);
          acc[1][nt] = __builtin_amdgcn_mfma_f32_16x16x32_bf16(a1, b, acc[1][nt], 0, 0, 0);
        }
      }
    }
    __syncthreads();
  }
#pragma unroll
  for (int mt = 0; mt < 2; mt++)
#pragma unroll
    for (int nt = 0; nt < 8; nt++)
      if (nt < ntiles)
#pragma unroll
        for (int i = 0; i < 4; i++) {
          int m = row0 + wave * 32 + mt * 16 + q * 4 + i;
          int j = nt * 16 + ml;
          float g = acc[mt][nt][i] + bias[j];
          if (mode == 0) {
            float s = 1.f / (1.f + __expf(-g));
            if (j < 64) out0[(size_t)m * out0s + j] = s * hstate[(size_t)m * hstride + j];
            else        ubuf[(size_t)m * 64 + (j - 64)] = s;
          } else {
            float cc = 1.f - 2.f / (__expf(2.f * g) + 1.f);  // tanh
            float uu = ubuf[(size_t)m * 64 + j];
            float hv = hstate[(size_t)m * hstride + j];
            out0[(size_t)m * out0s + j] = uu * hv + (1.f - uu) * cc;
          }
        }
  if (sdec) {
    if (tid < 128) {
      int m = row0 + tid;
      sdec[(size_t)m * 2 + 0] = C1s[(size_t)m * 80 + 64];
      sdec[(size_t)m * 2 + 1] = C2s[(size_t)m * 80 + 64];
    }
  }
  __syncthreads();
  for (int e = tid; e < 128 * 80; e += 256) {
    zero1[(size_t)row0 * 80 + e] = 0.f;
    zero2[(size_t)row0 * 80 + e] = 0.f;
  }
}

// ---------------- decoder prediction: x = h@W_pred + b; also writes d_out ----
__global__ __launch_bounds__(256) void pred_k(float* __restrict__ hx,
    const float* __restrict__ Wp, const float* __restrict__ bp,
    float* __restrict__ out, int t) {
  int m = blockIdx.x * 256 + threadIdx.x;
  if (m >= MPAD) return;
  const float* h = hx + (size_t)m * 80;
  float s = bp[0];
#pragma unroll
  for (int j = 0; j < 64; j++) s += h[j] * Wp[j];
  hx[(size_t)m * 80 + 64] = s;
  if (m < NN) out[(size_t)m * 12 + t] = s;
}

extern "C" void kernel_launch(void* const* d_in, const int* in_sizes, int n_in,
                              void* d_out, int out_size, void* d_ws, size_t ws_size,
                              hipStream_t stream) {
  const float* inputs = (const float*)d_in[0];
  const float* adj    = (const float*)d_in[2];
  const float* W_emb  = (const float*)d_in[3];
  const float* b_emb  = (const float*)d_in[4];
  const float* Wg_e   = (const float*)d_in[5];
  const float* bg_e   = (const float*)d_in[6];
  const float* Wc_e   = (const float*)d_in[7];
  const float* bc_e   = (const float*)d_in[8];
  const float* Wg_d   = (const float*)d_in[9];
  const float* bg_d   = (const float*)d_in[10];
  const float* Wc_d   = (const float*)d_in[11];
  const float* bc_d   = (const float*)d_in[12];
  const float* W_pred = (const float*)d_in[13];
  const float* b_pred = (const float*)d_in[14];
  float* out = (float*)d_out;
  char* ws = (char*)d_ws;

  size_t off = 0;
  auto alloc = [&](size_t bytes) -> void* {
    void* p = ws + off;
    off += (bytes + 511) & ~(size_t)511;
    return p;
  };
  u16*   A16    = (u16*)  alloc(200000000ULL);
  u16*   Ht     = (u16*)  alloc((size_t)96 * KPAD * 2);
  float* C1     = (float*)alloc((size_t)MPAD * 80 * 4);
  float* C2     = (float*)alloc((size_t)MPAD * 80 * 4);
  float* hx     = (float*)alloc((size_t)MPAD * 80 * 4);
  float* rh     = (float*)alloc((size_t)MPAD * 64 * 4);
  float* ub     = (float*)alloc((size_t)MPAD * 64 * 4);
  float* S1     = (float*)alloc((size_t)MPAD * 16 * 4);
  float* S2p    = (float*)alloc((size_t)MPAD * 16 * 4);
  float* sdec   = (float*)alloc((size_t)MPAD * 2 * 4);
  u16*   Wt_eg  = (u16*)  alloc(128 * 256 * 2);
  u16*   Wt_ec  = (u16*)  alloc(64 * 256 * 2);
  u16*   Wt_dg  = (u16*)  alloc(128 * 256 * 2);
  u16*   Wt_dc  = (u16*)  alloc(64 * 256 * 2);
  float* bias_eg= (float*)alloc(128 * 4);
  float* bias_ec= (float*)alloc(64 * 4);
  if (off > ws_size) return;  // ws too small: leaves out zeroed (absmax ~0.129 signal)

  hipMemsetAsync(C1, 0, (size_t)MPAD * 80 * 4, stream);
  hipMemsetAsync(C2, 0, (size_t)MPAD * 80 * 4, stream);
  hipMemsetAsync(hx, 0, (size_t)MPAD * 80 * 4, stream);
  hipMemsetAsync(S1, 0, (size_t)MPAD * 16 * 4, stream);
  hipMemsetAsync(S2p, 0, (size_t)MPAD * 16 * 4, stream);

  cvt_bf16<<<48829, 256, 0, stream>>>(adj, A16);
  build_w_enc<<<128, 256, 0, stream>>>(Wg_e, W_emb, b_emb, bg_e, 128, Wt_eg, bias_eg);
  build_w_enc<<<64, 256, 0, stream>>>(Wc_e, W_emb, b_emb, bc_e, 64, Wt_ec, bias_ec);
  build_w_dec<<<128, 256, 0, stream>>>(Wg_d, 128, Wt_dg);
  build_w_dec<<<64, 256, 0, stream>>>(Wc_d, 64, Wt_dc);

  dim3 ggrid(79, SPLITS);
  // encoder scalar-diffusion prepass: S1 = A@inputs, S2p = A@S1 (all 12 steps)
  prep_bt<<<512, 256, 0, stream>>>(inputs, 12, 12, 16, Ht);
  gemm_bt<<<ggrid, 256, 0, stream>>>(A16, Ht, S1, 1, 16);
  prep_bt<<<512, 256, 0, stream>>>(S1, 16, 16, 16, Ht);
  gemm_bt<<<ggrid, 256, 0, stream>>>(A16, Ht, S2p, 1, 16);

  for (int t = 0; t < 12; t++) {
    prep_bt<<<512, 256, 0, stream>>>(hx, 80, 64, 64, Ht);
    gemm_bt<<<ggrid, 256, 0, stream>>>(A16, Ht, C1, 4, 80);
    prep_bt<<<512, 256, 0, stream>>>(C1, 80, 64, 64, Ht);
    gemm_bt<<<ggrid, 256, 0, stream>>>(A16, Ht, C2, 4, 80);
    cellmm<<<79, 256, 0, stream>>>(hx, 80, C1, C2, inputs + t, 12, S1 + t, 16, S2p + t, 16,
        Wt_eg, bias_eg, 8, 0, hx, 80, rh, 64, ub, C1, C2, (float*)nullptr);
    prep_bt<<<512, 256, 0, stream>>>(rh, 64, 64, 64, Ht);
    gemm_bt<<<ggrid, 256, 0, stream>>>(A16, Ht, C1, 4, 80);
    prep_bt<<<512, 256, 0, stream>>>(C1, 80, 64, 64, Ht);
    gemm_bt<<<ggrid, 256, 0, stream>>>(A16, Ht, C2, 4, 80);
    cellmm<<<79, 256, 0, stream>>>(rh, 64, C1, C2, inputs + t, 12, S1 + t, 16, S2p + t, 16,
        Wt_ec, bias_ec, 4, 1, hx, 80, hx, 80, ub, C1, C2, (float*)nullptr);
  }
  for (int t = 0; t < 12; t++) {
    prep_bt<<<512, 256, 0, stream>>>(hx, 80, 80, 80, Ht);
    gemm_bt<<<ggrid, 256, 0, stream>>>(A16, Ht, C1, 5, 80);
    prep_bt<<<512, 256, 0, stream>>>(C1, 80, 80, 80, Ht);
    gemm_bt<<<ggrid, 256, 0, stream>>>(A16, Ht, C2, 5, 80);
    cellmm<<<79, 256, 0, stream>>>(hx, 80, C1, C2, hx + 64, 80, C1 + 64, 80, C2 + 64, 80,
        Wt_dg, bg_d, 8, 0, hx, 80, rh, 64, ub, C1, C2, sdec);
    prep_bt<<<512, 256, 0, stream>>>(rh, 64, 64, 64, Ht);
    gemm_bt<<<ggrid, 256, 0, stream>>>(A16, Ht, C1, 4, 80);
    prep_bt<<<512, 256, 0, stream>>>(C1, 80, 64, 64, Ht);
    gemm_bt<<<ggrid, 256, 0, stream>>>(A16, Ht, C2, 4, 80);
    cellmm<<<79, 256, 0, stream>>>(rh, 64, C1, C2, hx + 64, 80, sdec, 2, sdec + 1, 2,
        Wt_dc, bc_d, 4, 1, hx, 80, hx, 80, ub, C1, C2, (float*)nullptr);
    pred_k<<<40, 256, 0, stream>>>(hx, W_pred, b_pred, out, t);
  }
}

// Round 2
// 6978.627 us; speedup vs baseline: 1.2068x; 1.2068x over previous
//
#include <hip/hip_runtime.h>

// GTS forecasting (DCGRU enc-dec over dense 10000x10000 adjacency), gfx950.
// R2: atomic-free split-K (bf16 transposed partials + elementwise reducer),
// prep_bt eliminated (producers write transposed B operands directly).

typedef unsigned short u16;
typedef __attribute__((ext_vector_type(8))) short short8;
typedef __attribute__((ext_vector_type(8))) unsigned short u16x8;
typedef __attribute__((ext_vector_type(4))) unsigned short u16x4;
typedef __attribute__((ext_vector_type(4))) float f32x4;

#define NN 10000
#define P 10112          // padded m pitch (79*128)
#define KPAD 10048       // 157*64 k-chunks
#define SPLITS 13
#define KSPLIT 768       // 12 chunks per split; last split gets 13
#define PLANE 808960     // 80*P shorts per split plane

__device__ __forceinline__ u16 f2bf(float f) {
  unsigned u = __float_as_uint(f);
  unsigned r = (u + 0x7FFFu + ((u >> 16) & 1u)) >> 16;
  return (u16)r;
}
__device__ __forceinline__ float bf2f(u16 v) {
  return __uint_as_float((unsigned)v << 16);
}

__device__ __forceinline__ void load_lds16(const void* g, void* l) {
  __builtin_amdgcn_global_load_lds(
      (__attribute__((address_space(1))) void*)(void*)g,
      (__attribute__((address_space(3))) void*)l, 16, 0, 0);
}

// ---------------- fp32 -> bf16 convert of adjacency ----------------
__global__ __launch_bounds__(256) void cvt_bf16(const float* __restrict__ a,
                                                u16* __restrict__ o) {
  long i = ((long)blockIdx.x * 256 + threadIdx.x) * 8;
  if (i >= 100000000L) return;
  float4 x = *(const float4*)(a + i);
  float4 y = *(const float4*)(a + i + 4);
  u16x8 v;
  v[0]=f2bf(x.x); v[1]=f2bf(x.y); v[2]=f2bf(x.z); v[3]=f2bf(x.w);
  v[4]=f2bf(y.x); v[5]=f2bf(y.y); v[6]=f2bf(y.z); v[7]=f2bf(y.w);
  *(u16x8*)(o + i) = v;
}

// ---------------- transposed input embedding: Htin[c][m] = inputs[m][c] -----
__global__ __launch_bounds__(256) void prep_in(const float* __restrict__ in,
                                               u16* __restrict__ Htin) {
  int m = blockIdx.x * 256 + threadIdx.x;
  int c = blockIdx.y;
  if (m >= NN) return;
  Htin[(size_t)c * P + m] = f2bf(in[(size_t)m * 12 + c]);
}

// ---------------- combined weight builders ----------------
__global__ void build_w_enc(const float* __restrict__ W, const float* __restrict__ wemb,
    const float* __restrict__ bemb, const float* __restrict__ bsrc, int nout,
    u16* __restrict__ Wt, float* __restrict__ biasout) {
  int j = blockIdx.x, k = threadIdx.x;
  float v = 0.f;
  if (k < 64)        v = W[(64 + k) * nout + j] - W[(320 + k) * nout + j];
  else if (k < 128)  v = W[(192 + (k - 64)) * nout + j];
  else if (k < 192)  v = 2.f * W[(320 + (k - 128)) * nout + j];
  else if (k == 192) { float s = 0; for (int i = 0; i < 64; i++) s += wemb[i] * (W[i*nout+j] - W[(256+i)*nout+j]); v = s; }
  else if (k == 193) { float s = 0; for (int i = 0; i < 64; i++) s += wemb[i] * W[(128+i)*nout+j]; v = s; }
  else if (k == 194) { float s = 0; for (int i = 0; i < 64; i++) s += wemb[i] * W[(256+i)*nout+j]; v = 2.f * s; }
  Wt[j * 256 + k] = f2bf(v);
  if (k == 195) {
    float bb = bsrc[j];
    for (int i = 0; i < 64; i++) bb += bemb[i] * (W[i*nout+j] + W[(128+i)*nout+j] + W[(256+i)*nout+j]);
    biasout[j] = bb;
  }
}

__global__ void build_w_dec(const float* __restrict__ W, int nout, u16* __restrict__ Wt) {
  int j = blockIdx.x, k = threadIdx.x;
  float v = 0.f;
  if (k < 64)        v = W[(1 + k) * nout + j] - W[(131 + k) * nout + j];
  else if (k < 128)  v = W[(66 + (k - 64)) * nout + j];
  else if (k < 192)  v = 2.f * W[(131 + (k - 128)) * nout + j];
  else if (k == 192) v = W[0 * nout + j] - W[130 * nout + j];
  else if (k == 193) v = W[65 * nout + j];
  else if (k == 194) v = 2.f * W[130 * nout + j];
  Wt[j * 256 + k] = f2bf(v);
}

// ---------------- heavy pass: PT[s][c][m] = partial of (A @ Ht^T)^T ---------
__global__ __launch_bounds__(256) void gemm_bt(
    const u16* __restrict__ A, const u16* __restrict__ Ht,
    u16* __restrict__ PT, int ntiles) {
  __shared__ u16 Al[128 * 64];
  __shared__ u16 Bl[96 * 64];
  int tid = threadIdx.x;
  int wave = tid >> 6, lane = tid & 63, ml = lane & 15, q = lane >> 4;
  int row0 = blockIdx.x * 128;
  int kb = blockIdx.y * KSPLIT;
  int ke = (blockIdx.y == SPLITS - 1) ? KPAD : kb + KSPLIT;
  f32x4 acc[2][5] = {};
  int r8 = tid >> 3, c8 = tid & 7;
  int nrows_b = ntiles * 16;
  int biss = (nrows_b + 31) >> 5;
  for (int k0 = kb; k0 < ke; k0 += 64) {
    int kch = k0 + c8 * 8;
    int kcA = kch > 9992 ? 9992 : kch;  // clamp; Ht is zero past 10000
#pragma unroll
    for (int is = 0; is < 4; is++) {
      int row = row0 + is * 32 + r8;
      row = row > 9999 ? 9999 : row;
      load_lds16(A + (size_t)row * NN + kcA, (u16*)Al + is * 2048 + wave * 512);
    }
    for (int is = 0; is < biss; is++) {
      int br = is * 32 + r8;
      br = br >= nrows_b ? nrows_b - 1 : br;
      load_lds16(Ht + (size_t)br * P + k0 + c8 * 8, (u16*)Bl + is * 2048 + wave * 512);
    }
    __syncthreads();
#pragma unroll
    for (int kh = 0; kh < 2; kh++) {
      short8 a0 = *(const short8*)(Al + (wave * 32 + ml) * 64 + kh * 32 + q * 8);
      short8 a1 = *(const short8*)(Al + (wave * 32 + 16 + ml) * 64 + kh * 32 + q * 8);
#pragma unroll
      for (int nt = 0; nt < 5; nt++) {
        if (nt < ntiles) {
          short8 b = *(const short8*)(Bl + (nt * 16 + ml) * 64 + kh * 32 + q * 8);
          acc[0][nt] = __builtin_amdgcn_mfma_f32_16x16x32_bf16(a0, b, acc[0][nt], 0, 0, 0);
          acc[1][nt] = __builtin_amdgcn_mfma_f32_16x16x32_bf16(a1, b, acc[1][nt], 0, 0, 0);
        }
      }
    }
    __syncthreads();
  }
  u16* Pp = PT + (size_t)blockIdx.y * PLANE;
#pragma unroll
  for (int mt = 0; mt < 2; mt++)
#pragma unroll
    for (int nt = 0; nt < 5; nt++)
      if (nt < ntiles) {
        int j = nt * 16 + ml;
        int m = row0 + wave * 32 + mt * 16 + q * 4;
        u16x4 pk;
#pragma unroll
        for (int i = 0; i < 4; i++) pk[i] = f2bf(acc[mt][nt][i]);
        *(u16x4*)(Pp + (size_t)j * P + m) = pk;
      }
}

// ---------------- split reducer: T[c][m] = sum_s PT[s][c][m], zero m>=10000 -
__global__ __launch_bounds__(256) void red(const u16* __restrict__ PT,
                                           int ncols, u16* __restrict__ T) {
  int nch = ncols * 1264;  // P/8 chunks per col
  for (int cid = blockIdx.x * 256 + threadIdx.x; cid < nch; cid += gridDim.x * 256) {
    int c = cid / 1264;
    int mb8 = (cid - c * 1264) * 8;
    size_t base = (size_t)c * P + mb8;
    float a[8] = {};
#pragma unroll
    for (int s = 0; s < SPLITS; s++) {
      u16x8 v = *(const u16x8*)(PT + (size_t)s * PLANE + base);
#pragma unroll
      for (int i = 0; i < 8; i++) a[i] += bf2f(v[i]);
    }
    u16x8 o;
#pragma unroll
    for (int i = 0; i < 8; i++) o[i] = (mb8 >= NN) ? (u16)0 : f2bf(a[i]);
    *(u16x8*)(T + base) = o;
  }
}

// ---------------- fused cell projection (K=256) + GRU epilogue ----------------
__global__ __launch_bounds__(256) void cellmm(
    const u16* __restrict__ src0row,              // [m][64] bf16
    const u16* __restrict__ T1, const u16* __restrict__ T2,  // [c][P] bf16
    const u16* __restrict__ sc0, const u16* __restrict__ sc1,
    const u16* __restrict__ sc2,                  // bf16, unit m stride
    u16* __restrict__ sdec0, u16* __restrict__ sdec1,  // optional saves
    const u16* __restrict__ Wt, const float* __restrict__ bias,
    int ntiles, int mode,
    const float* __restrict__ hx,                 // fp32 [m][64]
    float* __restrict__ ubuf,                     // fp32 [m][64]
    float* __restrict__ hxout,                    // mode1 fp32 out
    u16* __restrict__ rowout,                     // bf16 [m][64]
    u16* __restrict__ htout) {                    // bf16 [j][P]
  __shared__ u16 Al[128 * 64];
  __shared__ u16 Wl[128 * 64];
  int tid = threadIdx.x;
  int wave = tid >> 6, lane = tid & 63, ml = lane & 15, q = lane >> 4;
  int m0 = blockIdx.x * 128;
  f32x4 acc[2][8] = {};
  for (int kc = 0; kc < 4; kc++) {
    if (kc == 0) {
#pragma unroll
      for (int is = 0; is < 4; is++) {
        int row = m0 + is * 32 + (tid >> 3);
        load_lds16(src0row + (size_t)row * 64 + (tid & 7) * 8,
                   (u16*)Al + is * 2048 + wave * 512);
      }
    } else if (kc < 3) {
      const u16* Ts = (kc == 1) ? T1 : T2;
      int c = tid >> 2;
      int mo = (tid & 3) * 32;
      const u16* sp = Ts + (size_t)c * P + m0 + mo;
      u16x8 v0 = *(const u16x8*)(sp);
      u16x8 v1 = *(const u16x8*)(sp + 8);
      u16x8 v2 = *(const u16x8*)(sp + 16);
      u16x8 v3 = *(const u16x8*)(sp + 24);
#pragma unroll
      for (int i = 0; i < 8; i++) {
        Al[(mo + i) * 64 + c]      = v0[i];
        Al[(mo + 8 + i) * 64 + c]  = v1[i];
        Al[(mo + 16 + i) * 64 + c] = v2[i];
        Al[(mo + 24 + i) * 64 + c] = v3[i];
      }
    } else {
      int r = tid >> 1, half = tid & 1;
      int m = m0 + r;
      u16* dst = Al + r * 64 + half * 32;
      if (half == 0) {
        u16 a = sc0[m], b = sc1[m], cc = sc2[m];
        dst[0] = a; dst[1] = b; dst[2] = cc;
#pragma unroll
        for (int jj = 3; jj < 32; jj++) dst[jj] = 0;
        if (sdec0) { sdec0[m] = b; sdec1[m] = cc; }
      } else {
#pragma unroll
        for (int jj = 0; jj < 32; jj++) dst[jj] = 0;
      }
    }
    int wiss = ntiles >> 1;
    for (int is = 0; is < wiss; is++) {
      int jr = is * 32 + (tid >> 3);
      load_lds16(Wt + (size_t)jr * 256 + kc * 64 + (tid & 7) * 8,
                 (u16*)Wl + is * 2048 + wave * 512);
    }
    __syncthreads();
#pragma unroll
    for (int kh = 0; kh < 2; kh++) {
      short8 a0 = *(const short8*)(Al + (wave * 32 + ml) * 64 + kh * 32 + q * 8);
      short8 a1 = *(const short8*)(Al + (wave * 32 + 16 + ml) * 64 + kh * 32 + q * 8);
#pragma unroll
      for (int nt = 0; nt < 8; nt++) {
        if (nt < ntiles) {
          short8 b = *(const short8*)(Wl + (nt * 16 + ml) * 64 + kh * 32 + q * 8);
          acc[0][nt] = __builtin_amdgcn_mfma_f32_16x16x32_bf16(a0, b, acc[0][nt], 0, 0, 0);
          acc[1][nt] = __builtin_amdgcn_mfma_f32_16x16x32_bf16(a1, b, acc[1][nt], 0, 0, 0);
        }
      }
    }
    __syncthreads();
  }
#pragma unroll
  for (int mt = 0; mt < 2; mt++)
#pragma unroll
    for (int nt = 0; nt < 8; nt++)
      if (nt < ntiles) {
        int j = nt * 16 + ml;
        int mb = m0 + wave * 32 + mt * 16 + q * 4;
        u16x4 pk;
        if (mode == 0) {
          if (j < 64) {
#pragma unroll
            for (int i = 0; i < 4; i++) {
              int m = mb + i;
              float g = acc[mt][nt][i] + bias[j];
              float s = 1.f / (1.f + __expf(-g));
              float rv = s * hx[(size_t)m * 64 + j];
              rowout[(size_t)m * 64 + j] = f2bf(rv);
              pk[i] = f2bf(rv);
            }
            if (mb < NN) *(u16x4*)(htout + (size_t)j * P + mb) = pk;
          } else {
#pragma unroll
            for (int i = 0; i < 4; i++) {
              int m = mb + i;
              float g = acc[mt][nt][i] + bias[j];
              ubuf[(size_t)m * 64 + (j - 64)] = 1.f / (1.f + __expf(-g));
            }
          }
        } else {
#pragma unroll
          for (int i = 0; i < 4; i++) {
            int m = mb + i;
            float g = acc[mt][nt][i] + bias[j];
            float cc = 1.f - 2.f / (__expf(2.f * g) + 1.f);
            float uu = ubuf[(size_t)m * 64 + j];
            float hv = hx[(size_t)m * 64 + j];
            float hn = uu * hv + (1.f - uu) * cc;
            hxout[(size_t)m * 64 + j] = hn;
            rowout[(size_t)m * 64 + j] = f2bf(hn);
            pk[i] = f2bf(hn);
          }
          if (mb < NN) *(u16x4*)(htout + (size_t)j * P + mb) = pk;
        }
      }
}

// ---------------- decoder prediction ----------------
__global__ __launch_bounds__(256) void pred_k(const float* __restrict__ hx,
    const float* __restrict__ Wp, const float* __restrict__ bp,
    float* __restrict__ out, u16* __restrict__ xrow, u16* __restrict__ Ht1,
    int t) {
  int m = blockIdx.x * 256 + threadIdx.x;
  if (m >= P) return;
  const float* h = hx + (size_t)m * 64;
  float s = bp[0];
#pragma unroll
  for (int j = 0; j < 64; j += 4) {
    float4 f = *(const float4*)(h + j);
    s += f.x * Wp[j] + f.y * Wp[j + 1] + f.z * Wp[j + 2] + f.w * Wp[j + 3];
  }
  u16 sb = f2bf(s);
  xrow[m] = sb;
  if (m < NN) {
    Ht1[(size_t)64 * P + m] = sb;
    out[(size_t)m * 12 + t] = s;
  }
}

extern "C" void kernel_launch(void* const* d_in, const int* in_sizes, int n_in,
                              void* d_out, int out_size, void* d_ws, size_t ws_size,
                              hipStream_t stream) {
  const float* inputs = (const float*)d_in[0];
  const float* adj    = (const float*)d_in[2];
  const float* W_emb  = (const float*)d_in[3];
  const float* b_emb  = (const float*)d_in[4];
  const float* Wg_e   = (const float*)d_in[5];
  const float* bg_e   = (const float*)d_in[6];
  const float* Wc_e   = (const float*)d_in[7];
  const float* bc_e   = (const float*)d_in[8];
  const float* Wg_d   = (const float*)d_in[9];
  const float* bg_d   = (const float*)d_in[10];
  const float* Wc_d   = (const float*)d_in[11];
  const float* bc_d   = (const float*)d_in[12];
  const float* W_pred = (const float*)d_in[13];
  const float* b_pred = (const float*)d_in[14];
  float* out = (float*)d_out;
  char* ws = (char*)d_ws;

  size_t off = 0;
  auto alloc = [&](size_t bytes) -> void* {
    void* p = ws + off;
    off += (bytes + 511) & ~(size_t)511;
    return p;
  };
  u16*   A16    = (u16*)  alloc(200000000ULL);
  u16*   PT1    = (u16*)  alloc((size_t)SPLITS * PLANE * 2);
  u16*   PT2    = (u16*)  alloc((size_t)SPLITS * PLANE * 2);
  u16*   Ht1    = (u16*)  alloc((size_t)80 * P * 2);
  u16*   T1     = (u16*)  alloc((size_t)80 * P * 2);
  u16*   T2     = (u16*)  alloc((size_t)80 * P * 2);
  u16*   HtR    = (u16*)  alloc((size_t)64 * P * 2);
  u16*   Htin   = (u16*)  alloc((size_t)16 * P * 2);
  u16*   Ts1    = (u16*)  alloc((size_t)16 * P * 2);
  u16*   Ts2    = (u16*)  alloc((size_t)16 * P * 2);
  float* hx     = (float*)alloc((size_t)P * 64 * 4);
  float* ub     = (float*)alloc((size_t)P * 64 * 4);
  u16*   hxrow  = (u16*)  alloc((size_t)P * 64 * 2);
  u16*   rhrow  = (u16*)  alloc((size_t)P * 64 * 2);
  u16*   xrow   = (u16*)  alloc((size_t)P * 2);
  u16*   sdec   = (u16*)  alloc((size_t)2 * P * 2);
  u16*   Wt_eg  = (u16*)  alloc(128 * 256 * 2);
  u16*   Wt_ec  = (u16*)  alloc(64 * 256 * 2);
  u16*   Wt_dg  = (u16*)  alloc(128 * 256 * 2);
  u16*   Wt_dc  = (u16*)  alloc(64 * 256 * 2);
  float* bias_eg= (float*)alloc(128 * 4);
  float* bias_ec= (float*)alloc(64 * 4);
  if (off > ws_size) return;  // ws too small (absmax ~0.129 signal)

  hipMemsetAsync(Ht1, 0, (size_t)80 * P * 2, stream);
  hipMemsetAsync(HtR, 0, (size_t)64 * P * 2, stream);
  hipMemsetAsync(Htin, 0, (size_t)16 * P * 2, stream);
  hipMemsetAsync(hx, 0, (size_t)P * 64 * 4, stream);
  hipMemsetAsync(hxrow, 0, (size_t)P * 64 * 2, stream);
  hipMemsetAsync(xrow, 0, (size_t)P * 2, stream);

  cvt_bf16<<<48829, 256, 0, stream>>>(adj, A16);
  prep_in<<<dim3(40, 12), 256, 0, stream>>>(inputs, Htin);
  build_w_enc<<<128, 256, 0, stream>>>(Wg_e, W_emb, b_emb, bg_e, 128, Wt_eg, bias_eg);
  build_w_enc<<<64, 256, 0, stream>>>(Wc_e, W_emb, b_emb, bc_e, 64, Wt_ec, bias_ec);
  build_w_dec<<<128, 256, 0, stream>>>(Wg_d, 128, Wt_dg);
  build_w_dec<<<64, 256, 0, stream>>>(Wc_d, 64, Wt_dc);

  dim3 ggrid(79, SPLITS);
  // scalar-diffusion prepass: Ts1 = (A@inputs)^T, Ts2 = (A@A@inputs)^T
  gemm_bt<<<ggrid, 256, 0, stream>>>(A16, Htin, PT1, 1);
  red<<<256, 256, 0, stream>>>(PT1, 16, Ts1);
  gemm_bt<<<ggrid, 256, 0, stream>>>(A16, Ts1, PT2, 1);
  red<<<256, 256, 0, stream>>>(PT2, 16, Ts2);

  for (int t = 0; t < 12; t++) {
    gemm_bt<<<ggrid, 256, 0, stream>>>(A16, Ht1, PT1, 4);
    red<<<256, 256, 0, stream>>>(PT1, 64, T1);
    gemm_bt<<<ggrid, 256, 0, stream>>>(A16, T1, PT2, 4);
    red<<<256, 256, 0, stream>>>(PT2, 64, T2);
    cellmm<<<79, 256, 0, stream>>>(hxrow, T1, T2,
        Htin + (size_t)t * P, Ts1 + (size_t)t * P, Ts2 + (size_t)t * P,
        (u16*)nullptr, (u16*)nullptr, Wt_eg, bias_eg, 8, 0,
        hx, ub, (float*)nullptr, rhrow, HtR);
    gemm_bt<<<ggrid, 256, 0, stream>>>(A16, HtR, PT1, 4);
    red<<<256, 256, 0, stream>>>(PT1, 64, T1);
    gemm_bt<<<ggrid, 256, 0, stream>>>(A16, T1, PT2, 4);
    red<<<256, 256, 0, stream>>>(PT2, 64, T2);
    cellmm<<<79, 256, 0, stream>>>(rhrow, T1, T2,
        Htin + (size_t)t * P, Ts1 + (size_t)t * P, Ts2 + (size_t)t * P,
        (u16*)nullptr, (u16*)nullptr, Wt_ec, bias_ec, 4, 1,
        hx, ub, hx, hxrow, Ht1);
  }
  for (int t = 0; t < 12; t++) {
    gemm_bt<<<ggrid, 256, 0, stream>>>(A16, Ht1, PT1, 5);
    red<<<256, 256, 0, stream>>>(PT1, 80, T1);
    gemm_bt<<<ggrid, 256, 0, stream>>>(A16, T1, PT2, 5);
    red<<<256, 256, 0, stream>>>(PT2, 80, T2);
    cellmm<<<79, 256, 0, stream>>>(hxrow, T1, T2,
        xrow, T1 + (size_t)64 * P, T2 + (size_t)64 * P,
        sdec, sdec + P, Wt_dg, bg_d, 8, 0,
        hx, ub, (float*)nullptr, rhrow, HtR);
    gemm_bt<<<ggrid, 256, 0, stream>>>(A16, HtR, PT1, 4);
    red<<<256, 256, 0, stream>>>(PT1, 64, T1);
    gemm_bt<<<ggrid, 256, 0, stream>>>(A16, T1, PT2, 4);
    red<<<256, 256, 0, stream>>>(PT2, 64, T2);
    cellmm<<<79, 256, 0, stream>>>(rhrow, T1, T2,
        xrow, sdec, sdec + P,
        (u16*)nullptr, (u16*)nullptr, Wt_dc, bc_d, 4, 1,
        hx, ub, hx, hxrow, Ht1);
    pred_k<<<40, 256, 0, stream>>>(hx, W_pred, b_pred, out, xrow, Ht1, t);
  }
}